// Round 1
// baseline (1900.836 us; speedup 1.0000x reference)
//
#include <hip/hip_runtime.h>
#include <hip/hip_bf16.h>
#include <math.h>

// Problem constants (from reference)
#define NSL 8000
#define EDIM 512
#define DI_ 1024
#define SDIM 16
#define NLAY 2
#define CHK 500

// ---------------- fp32 NT GEMM: C[m,n] = sum_k A[m*lda+k] * W[n*K+k] ----------------
#define BM 64
#define BN 128
#define BKK 16
#define AST 68    // BM+4 (68*4=272 bytes, 16B-aligned rows)
#define WST 132   // BN+4 (528 bytes, 16B-aligned rows)

template<int EPI>  // 0: none, 1: +bias, 2: softplus(x+bias)
__global__ __launch_bounds__(256)
void gemm_nt(const float* __restrict__ A, const float* __restrict__ W,
             const float* __restrict__ bias, float* __restrict__ C,
             int M, int N, int K, int lda)
{
    __shared__ float As[BKK][AST];
    __shared__ float Ws[BKK][WST];
    const int tid = threadIdx.x;
    const int m0 = blockIdx.y * BM;
    const int n0 = blockIdx.x * BN;
    const int tm = (tid & 15) * 4;   // 4 output rows
    const int tn = (tid >> 4) * 8;   // 8 output cols

    const int arow = tid >> 2;        // 0..63
    const int akq  = (tid & 3) * 4;   // 0,4,8,12

    const float* Ap  = A + (size_t)(m0 + arow) * lda + akq;
    const float* Wp1 = W + (size_t)(n0 + arow) * K + akq;
    const float* Wp2 = W + (size_t)(n0 + arow + 64) * K + akq;
    const bool wok1 = (n0 + arow) < N;
    const bool wok2 = (n0 + arow + 64) < N;

    float acc[4][8];
    #pragma unroll
    for (int i = 0; i < 4; ++i)
        #pragma unroll
        for (int j = 0; j < 8; ++j) acc[i][j] = 0.f;

    for (int k0 = 0; k0 < K; k0 += BKK) {
        float4 av  = *(const float4*)(Ap + k0);
        float4 wv1 = wok1 ? *(const float4*)(Wp1 + k0) : make_float4(0.f,0.f,0.f,0.f);
        float4 wv2 = wok2 ? *(const float4*)(Wp2 + k0) : make_float4(0.f,0.f,0.f,0.f);
        __syncthreads();
        As[akq+0][arow] = av.x;  As[akq+1][arow] = av.y;
        As[akq+2][arow] = av.z;  As[akq+3][arow] = av.w;
        Ws[akq+0][arow] = wv1.x; Ws[akq+1][arow] = wv1.y;
        Ws[akq+2][arow] = wv1.z; Ws[akq+3][arow] = wv1.w;
        Ws[akq+0][arow+64] = wv2.x; Ws[akq+1][arow+64] = wv2.y;
        Ws[akq+2][arow+64] = wv2.z; Ws[akq+3][arow+64] = wv2.w;
        __syncthreads();
        #pragma unroll
        for (int kk = 0; kk < BKK; ++kk) {
            float4 a4 = *(const float4*)&As[kk][tm];
            float4 b0 = *(const float4*)&Ws[kk][tn];
            float4 b1 = *(const float4*)&Ws[kk][tn+4];
            float a[4] = {a4.x,a4.y,a4.z,a4.w};
            float b[8] = {b0.x,b0.y,b0.z,b0.w,b1.x,b1.y,b1.z,b1.w};
            #pragma unroll
            for (int i = 0; i < 4; ++i)
                #pragma unroll
                for (int j = 0; j < 8; ++j)
                    acc[i][j] = fmaf(a[i], b[j], acc[i][j]);
        }
    }
    if (n0 + tn >= N) return;   // N%8==0 at every call site
    #pragma unroll
    for (int i = 0; i < 4; ++i) {
        size_t row = (size_t)(m0 + tm + i) * N + n0 + tn;
        float o[8];
        #pragma unroll
        for (int j = 0; j < 8; ++j) {
            float v = acc[i][j];
            if (EPI >= 1) v += bias[n0 + tn + j];
            if (EPI == 2) v = fmaxf(v, 0.f) + log1pf(__expf(-fabsf(v)));
            o[j] = v;
        }
        *(float4*)(C + row)     = make_float4(o[0],o[1],o[2],o[3]);
        *(float4*)(C + row + 4) = make_float4(o[4],o[5],o[6],o[7]);
    }
}

// ---------------- LayerNorm over 512 cols; optional residual; one wave per row ------
__global__ __launch_bounds__(256)
void ln_kernel(const float* __restrict__ in, const float* __restrict__ res,
               const float* __restrict__ g, const float* __restrict__ b,
               float* __restrict__ out)
{
    const int lane = threadIdx.x & 63;
    const int wv = threadIdx.x >> 6;
    const int row = blockIdx.x * 4 + wv;
    const size_t base = (size_t)row * EDIM + lane * 8;
    float x[8];
    float4 v0 = *(const float4*)(in + base);
    float4 v1 = *(const float4*)(in + base + 4);
    x[0]=v0.x; x[1]=v0.y; x[2]=v0.z; x[3]=v0.w;
    x[4]=v1.x; x[5]=v1.y; x[6]=v1.z; x[7]=v1.w;
    if (res) {
        float4 r0 = *(const float4*)(res + base);
        float4 r1 = *(const float4*)(res + base + 4);
        x[0]+=r0.x; x[1]+=r0.y; x[2]+=r0.z; x[3]+=r0.w;
        x[4]+=r1.x; x[5]+=r1.y; x[6]+=r1.z; x[7]+=r1.w;
    }
    float s = 0.f, sq = 0.f;
    #pragma unroll
    for (int j = 0; j < 8; ++j) { s += x[j]; sq += x[j]*x[j]; }
    #pragma unroll
    for (int off = 32; off; off >>= 1) {
        s  += __shfl_xor(s, off);
        sq += __shfl_xor(sq, off);
    }
    float mu = s * (1.f/EDIM);
    float var = sq * (1.f/EDIM) - mu*mu;
    float rs = rsqrtf(var + 1e-5f);
    const int col = lane * 8;
    float o[8];
    #pragma unroll
    for (int j = 0; j < 8; ++j)
        o[j] = (x[j] - mu) * rs * g[col+j] + b[col+j];
    *(float4*)(out + base)     = make_float4(o[0],o[1],o[2],o[3]);
    *(float4*)(out + base + 4) = make_float4(o[4],o[5],o[6],o[7]);
}

// ---------------- depthwise causal conv (DC=4) + SiLU -------------------------------
__global__ __launch_bounds__(256)
void conv_silu_k(const float* __restrict__ xz, const float* __restrict__ w,
                 const float* __restrict__ b, float* __restrict__ xc)
{
    const int d  = blockIdx.x * 256 + threadIdx.x;  // 0..1023
    const int lc = blockIdx.y;                      // 0..4 (chunks of 100)
    const int n  = blockIdx.z;                      // 0..15
    const int l0 = lc * 100;
    const float w0 = w[d*4+0], w1 = w[d*4+1], w2 = w[d*4+2], w3 = w[d*4+3];
    const float bb = b[d];
    const float* xp = xz + (size_t)n * CHK * 2048 + d;   // x = xz[..., :1024]
    float x0 = (l0-3) >= 0 ? xp[(size_t)(l0-3)*2048] : 0.f;
    float x1 = (l0-2) >= 0 ? xp[(size_t)(l0-2)*2048] : 0.f;
    float x2 = (l0-1) >= 0 ? xp[(size_t)(l0-1)*2048] : 0.f;
    float* yp = xc + ((size_t)n*CHK + l0) * DI_ + d;
    for (int l = 0; l < 100; ++l) {
        float x3 = xp[(size_t)(l0+l)*2048];
        float v = fmaf(w3,x3, fmaf(w2,x2, fmaf(w1,x1, fmaf(w0,x0, bb))));
        yp[(size_t)l*DI_] = v / (1.f + __expf(-v));  // silu
        x0 = x1; x1 = x2; x2 = x3;
    }
}

// ---------------- selective scan, fused:  y = (scan + x*D) * silu(z) ----------------
#define TBS 100
__global__ __launch_bounds__(256)
void scan_kernel(const float* __restrict__ dt, const float* __restrict__ xc,
                 const float* __restrict__ xz, const float* __restrict__ xdbl,
                 const float* __restrict__ Alog, const float* __restrict__ Dp,
                 float* __restrict__ y)
{
    __shared__ float BC[TBS][32];   // [t][0..15]=B, [16..31]=C
    const int d = blockIdx.x * 256 + threadIdx.x;  // 0..1023
    const int n = blockIdx.y;                      // 0..15
    float A[SDIM];
    #pragma unroll
    for (int s = 0; s < SDIM; ++s) A[s] = -__expf(Alog[d*SDIM + s]);
    const float Dv = Dp[d];
    float h[SDIM];
    #pragma unroll
    for (int s = 0; s < SDIM; ++s) h[s] = 0.f;
    const size_t roff = (size_t)n * CHK;
    for (int tb = 0; tb < CHK; tb += TBS) {
        __syncthreads();
        for (int idx = threadIdx.x; idx < TBS*32; idx += 256) {
            int t = idx >> 5, s = idx & 31;
            BC[t][s] = xdbl[(roff + tb + t)*80 + 32 + s];  // B (s<16) and C (s>=16)
        }
        __syncthreads();
        for (int t = 0; t < TBS; ++t) {
            const size_t p = roff + tb + t;
            float dtv = dt[p*DI_ + d];
            float xv  = xc[p*DI_ + d];
            float zv  = xz[p*2048 + DI_ + d];
            float dx  = dtv * xv;
            float accv = 0.f;
            #pragma unroll
            for (int s = 0; s < SDIM; ++s) {
                float dA = __expf(dtv * A[s]);
                h[s] = fmaf(dA, h[s], dx * BC[t][s]);
                accv = fmaf(h[s], BC[t][16+s], accv);
            }
            float yv = fmaf(xv, Dv, accv);
            float sz = zv / (1.f + __expf(-zv));
            y[p*DI_ + d] = yv * sz;
        }
    }
}

extern "C" void kernel_launch(void* const* d_in, const int* in_sizes, int n_in,
                              void* d_out, int out_size, void* d_ws, size_t ws_size,
                              hipStream_t stream) {
    (void)in_sizes; (void)n_in; (void)out_size; (void)ws_size;
    const float* sf       = (const float*)d_in[0];
    const float* ip_w     = (const float*)d_in[1];
    const float* ip_b     = (const float*)d_in[2];
    const float* ilng     = (const float*)d_in[3];
    const float* ilnb     = (const float*)d_in[4];
    const float* m_in_w   = (const float*)d_in[5];
    const float* m_conv_w = (const float*)d_in[6];
    const float* m_conv_b = (const float*)d_in[7];
    const float* m_xproj_w= (const float*)d_in[8];
    const float* m_dt_w   = (const float*)d_in[9];
    const float* m_dt_b   = (const float*)d_in[10];
    const float* m_Alog   = (const float*)d_in[11];
    const float* m_D      = (const float*)d_in[12];
    const float* m_out_w  = (const float*)d_in[13];
    const float* ln_g     = (const float*)d_in[14];
    const float* ln_b     = (const float*)d_in[15];
    const float* op_w     = (const float*)d_in[16];
    const float* op_b     = (const float*)d_in[17];
    float* outp = (float*)d_out;

    float* ws   = (float*)d_ws;
    float* t0   = ws;                              // 8000*512  (GEMM out / mamba out)
    float* h    = t0   + (size_t)NSL*EDIM;         // 8000*512  (stream state)
    float* xzb  = h    + (size_t)NSL*EDIM;         // 8000*2048
    float* xcb  = xzb  + (size_t)NSL*2048;         // 8000*1024 (conv out)
    float* xdbl = xcb  + (size_t)NSL*DI_;          // 8000*80
    float* dtb  = xdbl + (size_t)NSL*80;           // 8000*1024
    float* yb   = dtb  + (size_t)NSL*DI_;          // 8000*1024

    dim3 blk(256);
    // input proj + bias, then LN
    gemm_nt<1><<<dim3(4,125), blk, 0, stream>>>(sf, ip_w, ip_b, t0, NSL, EDIM, 512, 512);
    ln_kernel<<<2000, blk, 0, stream>>>(t0, nullptr, ilng, ilnb, h);

    for (int l = 0; l < NLAY; ++l) {
        // xz = h @ in_w^T  [8000,512] x [2048,512]^T
        gemm_nt<0><<<dim3(16,125), blk, 0, stream>>>(h, m_in_w + (size_t)l*2048*EDIM, nullptr, xzb, NSL, 2048, EDIM, EDIM);
        // depthwise causal conv + silu
        conv_silu_k<<<dim3(4,5,16), blk, 0, stream>>>(xzb, m_conv_w + (size_t)l*DI_*4, m_conv_b + (size_t)l*DI_, xcb);
        // x_dbl = xc @ xproj^T  [8000,1024] x [80,1024]^T
        gemm_nt<0><<<dim3(1,125), blk, 0, stream>>>(xcb, m_xproj_w + (size_t)l*80*DI_, nullptr, xdbl, NSL, 80, DI_, DI_);
        // dt = softplus(x_dbl[:, :32] @ dt_w^T + dt_b)  (lda=80 slices the 32-col view)
        gemm_nt<2><<<dim3(8,125), blk, 0, stream>>>(xdbl, m_dt_w + (size_t)l*DI_*32, m_dt_b + (size_t)l*DI_, dtb, NSL, DI_, 32, 80);
        // selective scan fused with +x*D and *silu(z)
        scan_kernel<<<dim3(4,16), blk, 0, stream>>>(dtb, xcb, xzb, xdbl, m_Alog + (size_t)l*DI_*SDIM, m_D + (size_t)l*DI_, yb);
        // mamba out proj  [8000,1024] x [512,1024]^T
        gemm_nt<0><<<dim3(4,125), blk, 0, stream>>>(yb, m_out_w + (size_t)l*EDIM*DI_, nullptr, t0, NSL, EDIM, DI_, DI_);
        // h = LN(mamba_out + h)   (in-place-safe: each wave reads its row before writing)
        ln_kernel<<<2000, blk, 0, stream>>>(t0, h, ln_g + (size_t)l*EDIM, ln_b + (size_t)l*EDIM, h);
    }
    // final projection
    gemm_nt<1><<<dim3(4,125), blk, 0, stream>>>(h, op_w, op_b, outp, NSL, EDIM, EDIM, EDIM);
}

// Round 2
// 922.147 us; speedup vs baseline: 2.0613x; 2.0613x over previous
//
#include <hip/hip_runtime.h>
#include <hip/hip_bf16.h>
#include <math.h>

// Problem constants
#define NSL 8000
#define MPAD 8064          // 63 * 128
#define EDIM 512
#define DI_ 1024
#define SDIM 16
#define NLAY 2
#define CHK 500
#define PSEG 10
#define LSEG 50

typedef __bf16 bf16_t;
typedef bf16_t bf16x8 __attribute__((ext_vector_type(8)));
typedef bf16_t bf16x4 __attribute__((ext_vector_type(4)));
typedef float  f32x4  __attribute__((ext_vector_type(4)));

#define GL2LDS(g, l) __builtin_amdgcn_global_load_lds( \
    (const __attribute__((address_space(1))) void*)(g), \
    (__attribute__((address_space(3))) void*)(l), 16, 0, 0)

// ================= split-bf16 MFMA GEMM: C = A*W^T (+bias) =================
// A_hi/A_lo: [MPAD][K] bf16 row-major; W_hi/W_lo: [N][K] bf16 row-major.
// 128x128 tile, BK=64, 4 waves of 64x64, mfma_f32_16x16x32_bf16.
template<int EPI>  // 0: none, 1: +bias
__global__ __launch_bounds__(256)
void gemm_mfma(const bf16_t* __restrict__ Ah, const bf16_t* __restrict__ Al,
               const bf16_t* __restrict__ Wh, const bf16_t* __restrict__ Wl,
               const float* __restrict__ bias, float* __restrict__ C,
               int M, int N, int K)
{
    __shared__ bf16_t sm[4 * 128 * 64];   // Ah | Al | Wh | Wl tiles, 64 KB
    const int tid = threadIdx.x;
    const int w   = tid >> 6;
    const int l   = tid & 63;
    const int m0  = blockIdx.y * 128;
    const int n0  = blockIdx.x * 128;

    const bf16_t* gb0 = Ah + (size_t)m0 * K;
    const bf16_t* gb1 = Al + (size_t)m0 * K;
    const bf16_t* gb2 = Wh + (size_t)n0 * K;
    const bf16_t* gb3 = Wl + (size_t)n0 * K;

    const int srow = l >> 3;          // 0..7 row within 8-row chunk
    const int scol = (l & 7) * 8;     // element col (16B per lane)

    const int wm = (w >> 1) * 64;
    const int wn = (w & 1) * 64;
    const int lr = l & 15;
    const int lk = (l >> 4) * 8;

    f32x4 acc[4][4];
    #pragma unroll
    for (int i = 0; i < 4; ++i)
        #pragma unroll
        for (int j = 0; j < 4; ++j) acc[i][j] = (f32x4){0.f,0.f,0.f,0.f};

    for (int kt = 0; kt < K; kt += 64) {
        // stage 4 x [128][64] bf16 tiles; 64 chunks of 1KB; wave w takes chunk 4*i+w
        #pragma unroll
        for (int i = 0; i < 16; ++i) {
            const int mat = i >> 2;                    // compile-time per iter
            const int lc  = ((i & 3) << 2) | w;        // 0..15
            const bf16_t* gsrc;
            if      (mat == 0) gsrc = gb0;
            else if (mat == 1) gsrc = gb1;
            else if (mat == 2) gsrc = gb2;
            else               gsrc = gb3;
            const bf16_t* gp = gsrc + (size_t)(lc * 8 + srow) * K + kt + scol;
            bf16_t* lp = sm + mat * 8192 + lc * 512;   // wave-uniform base
            GL2LDS(gp, lp);
        }
        __syncthreads();   // drains vmcnt: tiles visible
        #pragma unroll
        for (int ks = 0; ks < 2; ++ks) {
            bf16x8 ah[4], al[4], wh[4], wl[4];
            const int koff = ks * 32 + lk;
            #pragma unroll
            for (int f = 0; f < 4; ++f) {
                const int ar = wm + f * 16 + lr;
                const int wr = wn + f * 16 + lr;
                ah[f] = *(const bf16x8*)(sm + 0 * 8192 + ar * 64 + koff);
                al[f] = *(const bf16x8*)(sm + 1 * 8192 + ar * 64 + koff);
                wh[f] = *(const bf16x8*)(sm + 2 * 8192 + wr * 64 + koff);
                wl[f] = *(const bf16x8*)(sm + 3 * 8192 + wr * 64 + koff);
            }
            #pragma unroll
            for (int fi = 0; fi < 4; ++fi)
                #pragma unroll
                for (int fj = 0; fj < 4; ++fj) {
                    acc[fi][fj] = __builtin_amdgcn_mfma_f32_16x16x32_bf16(ah[fi], wh[fj], acc[fi][fj], 0, 0, 0);
                    acc[fi][fj] = __builtin_amdgcn_mfma_f32_16x16x32_bf16(ah[fi], wl[fj], acc[fi][fj], 0, 0, 0);
                    acc[fi][fj] = __builtin_amdgcn_mfma_f32_16x16x32_bf16(al[fi], wh[fj], acc[fi][fj], 0, 0, 0);
                }
        }
        __syncthreads();   // all reads done before next overwrite
    }
    // epilogue: C/D layout col=lane&15, row=(lane>>4)*4+reg  [m89/m91]
    const int r4 = (l >> 4) * 4;
    #pragma unroll
    for (int fj = 0; fj < 4; ++fj) {
        const int col = n0 + wn + fj * 16 + lr;
        const float bv = (EPI == 1) ? bias[col] : 0.f;
        #pragma unroll
        for (int fi = 0; fi < 4; ++fi) {
            const int rowb = m0 + wm + fi * 16 + r4;
            #pragma unroll
            for (int r = 0; r < 4; ++r) {
                const int row = rowb + r;
                if (row < M) C[(size_t)row * N + col] = acc[fi][fj][r] + bv;
            }
        }
    }
}

// ================= fp32 NT GEMM (kept for xproj N=80 and dt K=32) ===========
#define BM 64
#define BN 128
#define BKK 16
#define AST 68
#define WST 132

template<int EPI>  // 0: none, 2: softplus(x+bias)
__global__ __launch_bounds__(256)
void gemm_nt(const float* __restrict__ A, const float* __restrict__ W,
             const float* __restrict__ bias, float* __restrict__ C,
             int M, int N, int K, int lda)
{
    __shared__ float As[BKK][AST];
    __shared__ float Ws[BKK][WST];
    const int tid = threadIdx.x;
    const int m0 = blockIdx.y * BM;
    const int n0 = blockIdx.x * BN;
    const int tm = (tid & 15) * 4;
    const int tn = (tid >> 4) * 8;
    const int arow = tid >> 2;
    const int akq  = (tid & 3) * 4;

    const float* Ap  = A + (size_t)(m0 + arow) * lda + akq;
    const float* Wp1 = W + (size_t)(n0 + arow) * K + akq;
    const float* Wp2 = W + (size_t)(n0 + arow + 64) * K + akq;
    const bool wok1 = (n0 + arow) < N;
    const bool wok2 = (n0 + arow + 64) < N;

    float acc[4][8];
    #pragma unroll
    for (int i = 0; i < 4; ++i)
        #pragma unroll
        for (int j = 0; j < 8; ++j) acc[i][j] = 0.f;

    for (int k0 = 0; k0 < K; k0 += BKK) {
        float4 av  = *(const float4*)(Ap + k0);
        float4 wv1 = wok1 ? *(const float4*)(Wp1 + k0) : make_float4(0.f,0.f,0.f,0.f);
        float4 wv2 = wok2 ? *(const float4*)(Wp2 + k0) : make_float4(0.f,0.f,0.f,0.f);
        __syncthreads();
        As[akq+0][arow] = av.x;  As[akq+1][arow] = av.y;
        As[akq+2][arow] = av.z;  As[akq+3][arow] = av.w;
        Ws[akq+0][arow] = wv1.x; Ws[akq+1][arow] = wv1.y;
        Ws[akq+2][arow] = wv1.z; Ws[akq+3][arow] = wv1.w;
        Ws[akq+0][arow+64] = wv2.x; Ws[akq+1][arow+64] = wv2.y;
        Ws[akq+2][arow+64] = wv2.z; Ws[akq+3][arow+64] = wv2.w;
        __syncthreads();
        #pragma unroll
        for (int kk = 0; kk < BKK; ++kk) {
            float4 a4 = *(const float4*)&As[kk][tm];
            float4 b0 = *(const float4*)&Ws[kk][tn];
            float4 b1 = *(const float4*)&Ws[kk][tn+4];
            float a[4] = {a4.x,a4.y,a4.z,a4.w};
            float b[8] = {b0.x,b0.y,b0.z,b0.w,b1.x,b1.y,b1.z,b1.w};
            #pragma unroll
            for (int i = 0; i < 4; ++i)
                #pragma unroll
                for (int j = 0; j < 8; ++j)
                    acc[i][j] = fmaf(a[i], b[j], acc[i][j]);
        }
    }
    if (n0 + tn >= N) return;
    #pragma unroll
    for (int i = 0; i < 4; ++i) {
        size_t row = (size_t)(m0 + tm + i) * N + n0 + tn;
        float o[8];
        #pragma unroll
        for (int j = 0; j < 8; ++j) {
            float v = acc[i][j];
            if (EPI >= 1) v += bias[n0 + tn + j];
            if (EPI == 2) v = fmaxf(v, 0.f) + log1pf(__expf(-fabsf(v)));
            o[j] = v;
        }
        *(float4*)(C + row)     = make_float4(o[0],o[1],o[2],o[3]);
        *(float4*)(C + row + 4) = make_float4(o[4],o[5],o[6],o[7]);
    }
}

// ================= LayerNorm (+res) emitting fp32 + bf16 hi/lo ==============
__global__ __launch_bounds__(256)
void ln_kernel(const float* __restrict__ in, const float* __restrict__ res,
               const float* __restrict__ g, const float* __restrict__ b,
               float* __restrict__ out, bf16_t* __restrict__ oh, bf16_t* __restrict__ ol)
{
    const int lane = threadIdx.x & 63;
    const int wv = threadIdx.x >> 6;
    const int row = blockIdx.x * 4 + wv;
    const size_t base = (size_t)row * EDIM + lane * 8;
    float x[8];
    float4 v0 = *(const float4*)(in + base);
    float4 v1 = *(const float4*)(in + base + 4);
    x[0]=v0.x; x[1]=v0.y; x[2]=v0.z; x[3]=v0.w;
    x[4]=v1.x; x[5]=v1.y; x[6]=v1.z; x[7]=v1.w;
    if (res) {
        float4 r0 = *(const float4*)(res + base);
        float4 r1 = *(const float4*)(res + base + 4);
        x[0]+=r0.x; x[1]+=r0.y; x[2]+=r0.z; x[3]+=r0.w;
        x[4]+=r1.x; x[5]+=r1.y; x[6]+=r1.z; x[7]+=r1.w;
    }
    float s = 0.f, sq = 0.f;
    #pragma unroll
    for (int j = 0; j < 8; ++j) { s += x[j]; sq += x[j]*x[j]; }
    #pragma unroll
    for (int off = 32; off; off >>= 1) {
        s  += __shfl_xor(s, off);
        sq += __shfl_xor(sq, off);
    }
    float mu = s * (1.f/EDIM);
    float var = sq * (1.f/EDIM) - mu*mu;
    float rs = rsqrtf(var + 1e-5f);
    const int col = lane * 8;
    float o[8];
    bf16x8 vh, vl;
    #pragma unroll
    for (int j = 0; j < 8; ++j) {
        o[j] = (x[j] - mu) * rs * g[col+j] + b[col+j];
        bf16_t hb = (bf16_t)o[j];
        vh[j] = hb;
        vl[j] = (bf16_t)(o[j] - (float)hb);
    }
    *(float4*)(out + base)     = make_float4(o[0],o[1],o[2],o[3]);
    *(float4*)(out + base + 4) = make_float4(o[4],o[5],o[6],o[7]);
    *(bf16x8*)(oh + base) = vh;
    *(bf16x8*)(ol + base) = vl;
}

// ================= depthwise causal conv (DC=4) + SiLU ======================
__global__ __launch_bounds__(256)
void conv_silu_k(const float* __restrict__ xz, const float* __restrict__ w,
                 const float* __restrict__ b, float* __restrict__ xc)
{
    const int d  = blockIdx.x * 256 + threadIdx.x;
    const int lc = blockIdx.y;
    const int n  = blockIdx.z;
    const int l0 = lc * 100;
    const float w0 = w[d*4+0], w1 = w[d*4+1], w2 = w[d*4+2], w3 = w[d*4+3];
    const float bb = b[d];
    const float* xp = xz + (size_t)n * CHK * 2048 + d;
    float x0 = (l0-3) >= 0 ? xp[(size_t)(l0-3)*2048] : 0.f;
    float x1 = (l0-2) >= 0 ? xp[(size_t)(l0-2)*2048] : 0.f;
    float x2 = (l0-1) >= 0 ? xp[(size_t)(l0-1)*2048] : 0.f;
    float* yp = xc + ((size_t)n*CHK + l0) * DI_ + d;
    for (int l = 0; l < 100; ++l) {
        float x3 = xp[(size_t)(l0+l)*2048];
        float v = fmaf(w3,x3, fmaf(w2,x2, fmaf(w1,x1, fmaf(w0,x0, bb))));
        yp[(size_t)l*DI_] = v / (1.f + __expf(-v));
        x0 = x1; x1 = x2; x2 = x3;
    }
}

// ================= segmented selective scan (3 phases) ======================
// S1: per-segment prod(dA) and local scan end-state.
__global__ __launch_bounds__(256)
void sc_part(const float* __restrict__ dt, const float* __restrict__ xc,
             const float* __restrict__ xdbl, const float* __restrict__ Alog,
             float* __restrict__ pA, float* __restrict__ loc)
{
    __shared__ float Bs[LSEG][SDIM];
    const int d  = blockIdx.x * 256 + threadIdx.x;
    const int n  = blockIdx.y;
    const int sg = blockIdx.z;
    const int t0 = sg * LSEG;
    for (int idx = threadIdx.x; idx < LSEG*SDIM; idx += 256) {
        int t = idx >> 4, s = idx & 15;
        Bs[t][s] = xdbl[((size_t)(n*CHK + t0 + t))*80 + 32 + s];
    }
    __syncthreads();
    float A[SDIM], p[SDIM], lc[SDIM];
    #pragma unroll
    for (int s = 0; s < SDIM; ++s) {
        A[s] = -__expf(Alog[d*SDIM + s]); p[s] = 1.f; lc[s] = 0.f;
    }
    const size_t rb = (size_t)n*CHK + t0;
    for (int t = 0; t < LSEG; ++t) {
        float dtv = dt[(rb+t)*DI_ + d];
        float xv  = xc[(rb+t)*DI_ + d];
        float dx = dtv * xv;
        #pragma unroll
        for (int s = 0; s < SDIM; ++s) {
            float dA = __expf(dtv * A[s]);
            p[s] *= dA;
            lc[s] = fmaf(dA, lc[s], dx * Bs[t][s]);
        }
    }
    const size_t ob = ((size_t)(n*PSEG + sg) << 14) + d*16;
    #pragma unroll
    for (int s = 0; s < SDIM; s += 4) {
        *(float4*)(pA  + ob + s) = make_float4(p[s],p[s+1],p[s+2],p[s+3]);
        *(float4*)(loc + ob + s) = make_float4(lc[s],lc[s+1],lc[s+2],lc[s+3]);
    }
}

// S2: cross-segment prefix; overwrites loc[idx] with the segment's INCOMING state.
__global__ __launch_bounds__(256)
void sc_comb(const float* __restrict__ pA, float* __restrict__ hio)
{
    const int gI = blockIdx.x * 256 + threadIdx.x;   // 0..262143
    const int n = gI >> 14;
    const int r = gI & 16383;
    float h = 0.f;
    #pragma unroll
    for (int sg = 0; sg < PSEG; ++sg) {
        size_t idx = ((size_t)(n*PSEG + sg) << 14) + r;
        float pa = pA[idx];
        float lo = hio[idx];
        hio[idx] = h;
        h = fmaf(pa, h, lo);
    }
}

// S3: re-run each segment from its incoming state; fuse +x*D, *silu(z), bf16 hi/lo out.
__global__ __launch_bounds__(256)
void sc_fin(const float* __restrict__ dt, const float* __restrict__ xc,
            const float* __restrict__ xz, const float* __restrict__ xdbl,
            const float* __restrict__ Alog, const float* __restrict__ Dp,
            const float* __restrict__ hin, bf16_t* __restrict__ yh, bf16_t* __restrict__ yl)
{
    __shared__ float BCs[LSEG][32];
    const int d  = blockIdx.x * 256 + threadIdx.x;
    const int n  = blockIdx.y;
    const int sg = blockIdx.z;
    const int t0 = sg * LSEG;
    for (int idx = threadIdx.x; idx < LSEG*32; idx += 256) {
        int t = idx >> 5, s = idx & 31;
        BCs[t][s] = xdbl[((size_t)(n*CHK + t0 + t))*80 + 32 + s];
    }
    __syncthreads();
    float A[SDIM], h[SDIM];
    #pragma unroll
    for (int s = 0; s < SDIM; ++s) A[s] = -__expf(Alog[d*SDIM + s]);
    const size_t hb = ((size_t)(n*PSEG + sg) << 14) + d*16;
    #pragma unroll
    for (int s = 0; s < SDIM; ++s) h[s] = hin[hb + s];
    const float Dv = Dp[d];
    const size_t rb = (size_t)n*CHK + t0;
    for (int t = 0; t < LSEG; ++t) {
        const size_t p = rb + t;
        float dtv = dt[p*DI_ + d];
        float xv  = xc[p*DI_ + d];
        float zv  = xz[p*2048 + DI_ + d];
        float dx = dtv * xv;
        float accv = 0.f;
        #pragma unroll
        for (int s = 0; s < SDIM; ++s) {
            float dA = __expf(dtv * A[s]);
            h[s] = fmaf(dA, h[s], dx * BCs[t][s]);
            accv = fmaf(h[s], BCs[t][16+s], accv);
        }
        float yv = fmaf(xv, Dv, accv);
        float sz = zv / (1.f + __expf(-zv));
        float outv = yv * sz;
        bf16_t oh = (bf16_t)outv;
        yh[p*DI_ + d] = oh;
        yl[p*DI_ + d] = (bf16_t)(outv - (float)oh);
    }
}

// ================= fp32 -> bf16 hi/lo split (pad region zeroed) =============
__global__ __launch_bounds__(256)
void convert_split(const float* __restrict__ src, bf16_t* __restrict__ hi,
                   bf16_t* __restrict__ lo, long n, long valid)
{
    long i = ((long)blockIdx.x * 256 + threadIdx.x) * 4;
    if (i >= n) return;
    float4 v = make_float4(0.f,0.f,0.f,0.f);
    if (i < valid) v = *(const float4*)(src + i);
    float a[4] = {v.x, v.y, v.z, v.w};
    bf16x4 vh, vl;
    #pragma unroll
    for (int j = 0; j < 4; ++j) {
        bf16_t hb = (bf16_t)a[j];
        vh[j] = hb;
        vl[j] = (bf16_t)(a[j] - (float)hb);
    }
    *(bf16x4*)(hi + i) = vh;
    *(bf16x4*)(lo + i) = vl;
}

__global__ __launch_bounds__(256)
void zero_bf16(bf16_t* __restrict__ p, long n)
{
    long i = ((long)blockIdx.x * 256 + threadIdx.x) * 8;
    if (i < n) *(int4*)(p + i) = make_int4(0,0,0,0);
}

// ============================================================================
extern "C" void kernel_launch(void* const* d_in, const int* in_sizes, int n_in,
                              void* d_out, int out_size, void* d_ws, size_t ws_size,
                              hipStream_t stream) {
    (void)in_sizes; (void)n_in; (void)out_size; (void)ws_size;
    const float* sf       = (const float*)d_in[0];
    const float* ip_w     = (const float*)d_in[1];
    const float* ip_b     = (const float*)d_in[2];
    const float* ilng     = (const float*)d_in[3];
    const float* ilnb     = (const float*)d_in[4];
    const float* m_in_w   = (const float*)d_in[5];
    const float* m_conv_w = (const float*)d_in[6];
    const float* m_conv_b = (const float*)d_in[7];
    const float* m_xproj_w= (const float*)d_in[8];
    const float* m_dt_w   = (const float*)d_in[9];
    const float* m_dt_b   = (const float*)d_in[10];
    const float* m_Alog   = (const float*)d_in[11];
    const float* m_D      = (const float*)d_in[12];
    const float* m_out_w  = (const float*)d_in[13];
    const float* ln_g     = (const float*)d_in[14];
    const float* ln_b     = (const float*)d_in[15];
    const float* op_w     = (const float*)d_in[16];
    const float* op_b     = (const float*)d_in[17];
    float* outp = (float*)d_out;

    // -------- workspace layout --------
    float* t0   = (float*)d_ws;                    // 8000*512
    float* h    = t0   + 4096000;                  // 8000*512
    float* xzb  = h    + 4096000;                  // 8000*2048
    float* xcb  = xzb  + 16384000;                 // 8000*1024
    float* xdbl = xcb  + 8192000;                  // 8000*80
    float* dtb  = xdbl + 640000;                   // 8000*1024
    float* pAb  = dtb  + 8192000;                  // 16*10*1024*16
    float* locb = pAb  + 2621440;                  // 16*10*1024*16
    bf16_t* sfh = (bf16_t*)(locb + 2621440);       // 8064*512 each
    bf16_t* sfl = sfh + 4128768;
    bf16_t* hh  = sfl + 4128768;
    bf16_t* hl  = hh  + 4128768;
    bf16_t* yh  = hl  + 4128768;                   // 8064*1024 each
    bf16_t* yl  = yh  + 8257536;
    bf16_t* wiph = yl + 8257536;                   // 512*512
    bf16_t* wipl = wiph + 262144;
    bf16_t* winh = wipl + 262144;                  // 2*2048*512
    bf16_t* winl = winh + 2097152;
    bf16_t* wouth= winl + 2097152;                 // 2*512*1024
    bf16_t* woutl= wouth + 1048576;
    bf16_t* woph = woutl + 1048576;                // 512*512
    bf16_t* wopl = woph + 262144;

    dim3 blk(256);
    // -------- weight + input conversions (every call; weights are ~15 MB) ----
    convert_split<<<256,  blk, 0, stream>>>(ip_w,    wiph, wipl, 262144,  262144);
    convert_split<<<2048, blk, 0, stream>>>(m_in_w,  winh, winl, 2097152, 2097152);
    convert_split<<<1024, blk, 0, stream>>>(m_out_w, wouth,woutl,1048576, 1048576);
    convert_split<<<256,  blk, 0, stream>>>(op_w,    woph, wopl, 262144,  262144);
    convert_split<<<4032, blk, 0, stream>>>(sf,      sfh,  sfl,  4128768, 4096000);
    // zero pad rows (8000..8063) of h and y bf16 buffers
    zero_bf16<<<16, blk, 0, stream>>>(hh + 4096000, 32768);
    zero_bf16<<<16, blk, 0, stream>>>(hl + 4096000, 32768);
    zero_bf16<<<32, blk, 0, stream>>>(yh + 8192000, 65536);
    zero_bf16<<<32, blk, 0, stream>>>(yl + 8192000, 65536);

    // -------- input projection + LN --------
    gemm_mfma<1><<<dim3(4,63), blk, 0, stream>>>(sfh, sfl, wiph, wipl, ip_b, t0, NSL, EDIM, 512);
    ln_kernel<<<2000, blk, 0, stream>>>(t0, nullptr, ilng, ilnb, h, hh, hl);

    for (int l = 0; l < NLAY; ++l) {
        // xz = h @ in_w^T   [8000,512] x [2048,512]^T
        gemm_mfma<0><<<dim3(16,63), blk, 0, stream>>>(hh, hl, winh + (size_t)l*1048576, winl + (size_t)l*1048576,
                                                      nullptr, xzb, NSL, 2048, EDIM);
        conv_silu_k<<<dim3(4,5,16), blk, 0, stream>>>(xzb, m_conv_w + (size_t)l*DI_*4, m_conv_b + (size_t)l*DI_, xcb);
        // x_dbl = xc @ xproj^T  (fp32, N=80)
        gemm_nt<0><<<dim3(1,125), blk, 0, stream>>>(xcb, m_xproj_w + (size_t)l*80*DI_, nullptr, xdbl, NSL, 80, DI_, DI_);
        // dt = softplus(x_dbl[:, :32] @ dt_w^T + dt_b)  (fp32, K=32, lda=80)
        gemm_nt<2><<<dim3(8,125), blk, 0, stream>>>(xdbl, m_dt_w + (size_t)l*DI_*32, m_dt_b + (size_t)l*DI_, dtb, NSL, DI_, 32, 80);
        // segmented scan
        sc_part<<<dim3(4,16,PSEG), blk, 0, stream>>>(dtb, xcb, xdbl, m_Alog + (size_t)l*DI_*SDIM, pAb, locb);
        sc_comb<<<1024, blk, 0, stream>>>(pAb, locb);
        sc_fin<<<dim3(4,16,PSEG), blk, 0, stream>>>(dtb, xcb, xzb, xdbl, m_Alog + (size_t)l*DI_*SDIM,
                                                    m_D + (size_t)l*DI_, locb, yh, yl);
        // mamba out proj  [8000,1024] x [512,1024]^T
        gemm_mfma<0><<<dim3(4,63), blk, 0, stream>>>(yh, yl, wouth + (size_t)l*524288, woutl + (size_t)l*524288,
                                                     nullptr, t0, NSL, EDIM, DI_);
        // h = LN(mamba_out + h), also emit bf16 hi/lo
        ln_kernel<<<2000, blk, 0, stream>>>(t0, h, ln_g + (size_t)l*EDIM, ln_b + (size_t)l*EDIM, h, hh, hl);
    }
    // final projection (fp32 out with bias)
    gemm_mfma<1><<<dim3(4,63), blk, 0, stream>>>(hh, hl, woph, wopl, op_b, outp, NSL, EDIM, 512);
}